// Round 11
// baseline (465.115 us; speedup 1.0000x reference)
//
#include <hip/hip_runtime.h>
#include <cstddef>
#include <cstdint>

#define S3 32768  // 32*32*32 spatial positions

typedef short bf16x8 __attribute__((ext_vector_type(8)));   // 8 bf16 in 4 VGPRs
typedef float f32x16 __attribute__((ext_vector_type(16)));

static __device__ inline unsigned short f2bf(float f) {
    unsigned int u = __float_as_uint(f);
    unsigned int r = (u + 0x7FFFu + ((u >> 16) & 1u)) >> 16;  // RNE
    return (unsigned short)r;
}

static __device__ inline float bf2f(unsigned short u) {
    return __uint_as_float(((unsigned)u) << 16);
}

// --------- weight transpose: wT[tap][icb][c][kb][chunk(=half*32+ln)][8ic] --
// NEW (r11): LDS-tiled, coalesced-read version. The old one-thread-one-elem
// kernel read w at 500B lane stride (4B used per 64B line, ~16x FETCH
// amplification on a 16MB source). Now: 1 block per oc; stage-1 reads the
// oc's 125*IC floats CONTIGUOUSLY (float4), bf16-converts into LDS
// tile[ic][tap] (pad 130 so the stage-2 column gather walks banks);
// stage-2 gathers 8 consecutive ic at fixed tap and writes the SAME wT
// index as before (16B uint4 runs). Output layout bit-identical.
template <int IC, int OC>
__global__ __launch_bounds__(256) void wt_transpose(
    const float* __restrict__ w, unsigned short* __restrict__ wT)
{
    constexpr int ICB = IC / 32, WOC = OC / 32;
    constexpr int NFLAT = IC * 125;          // floats per oc (divisible by 4)
    constexpr int NRUNS = 125 * ICB * 4;     // uint4 runs per oc
    __shared__ unsigned short tile[IC][130];
    const int oc = blockIdx.x, tid = threadIdx.x;
    const int ln = oc & 31, c = oc >> 5;
    const float* src = w + (size_t)oc * NFLAT;

    for (int f = tid; f < NFLAT / 4; f += 256) {
        float4 v = *(const float4*)(src + f * 4);
        float vv[4] = {v.x, v.y, v.z, v.w};
#pragma unroll
        for (int i = 0; i < 4; ++i) {
            int flat = f * 4 + i;
            int ic = flat / 125, tap = flat - ic * 125;
            tile[ic][tap] = f2bf(vv[i]);
        }
    }
    __syncthreads();
    for (int r = tid; r < NRUNS; r += 256) {
        int tap = r / (ICB * 4);
        int rem = r - tap * (ICB * 4);
        int icb = rem >> 2, kb = (rem >> 1) & 1, half = rem & 1;
        int ic0 = icb * 32 + kb * 16 + half * 8;
        __align__(16) unsigned short tmp[8];
#pragma unroll
        for (int e = 0; e < 8; ++e) tmp[e] = tile[ic0 + e][tap];
        size_t t = ((((size_t)(tap * ICB + icb) * WOC + c) * 2 + kb) * 64 +
                    half * 32 + ln) * 8;
        *(uint4*)(wT + t) = *(const uint4*)tmp;
    }
}

// ---------------- x transpose: xb[b][z][y][x][128 ic] bf16 -----------------
__global__ __launch_bounds__(256) void xb_transpose(
    const float* __restrict__ x, unsigned short* __restrict__ xb)
{
    __shared__ float tile[32][133];
    int zy = blockIdx.x, b = blockIdx.y;
    int t = threadIdx.x, xi = t & 31, ich = t >> 5;
#pragma unroll
    for (int k = 0; k < 16; ++k) {
        int ic = k * 8 + ich;
        tile[xi][ic] = x[(size_t)(b * 128 + ic) * S3 + zy * 32 + xi];
    }
    __syncthreads();
#pragma unroll
    for (int k = 0; k < 2; ++k) {
        int u = t + 256 * k;
        int xx = u >> 4, j = u & 15;
        __align__(16) unsigned short tmp[8];
#pragma unroll
        for (int e = 0; e < 8; ++e) tmp[e] = f2bf(tile[xx][j * 8 + e]);
        *(uint4*)(xb + ((size_t)b * S3 + zy * 32 + xx) * 128 + j * 8) =
            *(const uint4*)tmp;
    }
}

// --- token/q: qbuf fp32 [oc][s]; tokb bf16 [s][32c] (B-fragment-ready) -----
__global__ __launch_bounds__(256) void token_q_kernel(
    const float* __restrict__ basis, const float* __restrict__ mixer,
    const float* __restrict__ wq, unsigned short* __restrict__ tokb,
    float* __restrict__ qbuf)
{
    int s = blockIdx.x * 256 + threadIdx.x;
    float tok[32];
#pragma unroll
    for (int c = 0; c < 32; ++c) tok[c] = 0.f;
#pragma unroll
    for (int r = 0; r < 8; ++r) {
        float bv = basis[r * S3 + s];
#pragma unroll
        for (int c = 0; c < 32; ++c) tok[c] += mixer[c * 8 + r] * bv;
    }
    __align__(16) unsigned short tb[32];
#pragma unroll
    for (int c = 0; c < 32; ++c) tb[c] = f2bf(tok[c]);
#pragma unroll
    for (int k = 0; k < 4; ++k)
        *(uint4*)(tokb + (size_t)s * 32 + k * 8) = *(const uint4*)(tb + k * 8);
    const float* wq4 = wq + 4 * 1024;
#pragma unroll
    for (int o = 0; o < 32; ++o) {
        float a = 0.f;
#pragma unroll
        for (int c = 0; c < 32; ++c) a += wq4[o * 32 + c] * tok[c];
        qbuf[o * S3 + s] = a;
    }
}

// ------------- attention via MFMA (r10, measured win — UNCHANGED) ----------
// Fragment conventions reused from the PROVEN conv kernel:
//   A: lane(ln,half) holds W[oc=ln][c=kb*16+half*8+e]
//   B: lane(ln,half) holds X[c=kb*16+half*8+e][col=ln]
//   C: reg r -> row=(r&3)+8*(r>>2)+4*half, col=ln
__global__ __launch_bounds__(256) void attention_mfma(
    const unsigned short* __restrict__ xb, const unsigned short* __restrict__ tokb,
    const float* __restrict__ qbuf, const float* __restrict__ wk,
    const float* __restrict__ wv, const float* __restrict__ alpha_p,
    float* __restrict__ out)
{
    const int wave = threadIdx.x >> 6, lane = threadIdx.x & 63;
    const int ln = lane & 31, half = lane >> 5;
    const int tl = blockIdx.x * 4 + wave;     // 4096 tiles
    const int g0 = tl * 32;
    const int b = g0 >> 15;
    const int s0 = g0 & (S3 - 1);

    // ---- A fragments: Wk/Wv, loaded once per wave (L2-hot, 20 KB each) ----
    bf16x8 ak[5][2], av[5][2];
#pragma unroll
    for (int j = 0; j < 5; ++j)
#pragma unroll
        for (int kb = 0; kb < 2; ++kb) {
            const float* ks = wk + ((j * 32 + ln) * 32 + kb * 16 + half * 8);
            const float* vs = wv + ((j * 32 + ln) * 32 + kb * 16 + half * 8);
            bf16x8 tk, tv;
#pragma unroll
            for (int e = 0; e < 8; ++e) {
                tk[e] = (short)f2bf(ks[e]);
                tv[e] = (short)f2bf(vs[e]);
            }
            ak[j][kb] = tk;
            av[j][kb] = tv;
        }

    // ---- q registers: q[row(r,half)][s0+ln], coalesced over lanes ----
    float qv[16];
#pragma unroll
    for (int r = 0; r < 16; ++r) {
        int row = (r & 3) + 8 * (r >> 2) + 4 * half;
        qv[r] = qbuf[(size_t)row * S3 + s0 + ln];
    }

    const unsigned short* xrow = xb + ((size_t)b * S3 + s0 + ln) * 128;
    const unsigned short* trow = tokb + (size_t)(s0 + ln) * 32;

    auto loadB = [&](int j, int kb) -> bf16x8 {
        if (j < 4)
            return *(const bf16x8*)(xrow + j * 32 + kb * 16 + half * 8);
        else
            return *(const bf16x8*)(trow + kb * 16 + half * 8);
    };

    // ---- QK^T pass ----
    const float scale = 0.17677669529663687f;
    float l[5];
#pragma unroll
    for (int j = 0; j < 5; ++j) {
        bf16x8 b0 = loadB(j, 0), b1 = loadB(j, 1);
        f32x16 c;
#pragma unroll
        for (int e = 0; e < 16; ++e) c[e] = 0.f;
        c = __builtin_amdgcn_mfma_f32_32x32x16_bf16(ak[j][0], b0, c, 0, 0, 0);
        c = __builtin_amdgcn_mfma_f32_32x32x16_bf16(ak[j][1], b1, c, 0, 0, 0);
        float part = 0.f;
#pragma unroll
        for (int r = 0; r < 16; ++r) part += c[r] * qv[r];
        part += __shfl_xor(part, 32);     // combine the two half rows
        l[j] = part * scale;
    }

    // ---- softmax (lane-local: each lane owns its column) ----
    float m = l[0];
#pragma unroll
    for (int j = 1; j < 5; ++j) m = fmaxf(m, l[j]);
    float p[5], sum = 0.f;
#pragma unroll
    for (int j = 0; j < 5; ++j) { p[j] = __expf(l[j] - m); sum += p[j]; }
    float inv = alpha_p[0] / sum;

    // ---- PV pass: p_j folded into B operand (per-lane = per-column) ----
    f32x16 ov;
#pragma unroll
    for (int e = 0; e < 16; ++e) ov[e] = 0.f;
#pragma unroll
    for (int j = 0; j < 5; ++j) {
        float pj = p[j];
#pragma unroll
        for (int kb = 0; kb < 2; ++kb) {
            bf16x8 bx = loadB(j, kb);
            bf16x8 pb;
#pragma unroll
            for (int e = 0; e < 8; ++e)
                pb[e] = (short)f2bf(bf2f((unsigned short)bx[e]) * pj);
            ov = __builtin_amdgcn_mfma_f32_32x32x16_bf16(av[j][kb], pb, ov,
                                                         0, 0, 0);
        }
    }

    // ---- write: out[(b*32+row)][s0+ln] (half-wave rows cover all 32 oc) ----
#pragma unroll
    for (int r = 0; r < 16; ++r) {
        int row = (r & 3) + 8 * (r >> 2) + 4 * half;
        out[((size_t)b * 32 + row) * S3 + s0 + ln] = ov[r] * inv;
    }
}

// ============ conv1: round-1 exact kernel (222.1 µs r1, 219.5 µs r10) ======
// 512-thread block (8 waves), 1 block/CU, block tile OC x (16y x 32x) x 1z.
// 2 oc-halves x 4 y-waves, JT=4. LDS input double-buffer, stage overlapped
// at gp==2, one raw lgkmcnt(0)+s_barrier per window. kb-split conv1
// ABANDONED (r4: spill; r8: diet still spilled + broke latency hiding).
template <int IC, int OC, bool WRITE_H>
__global__ __launch_bounds__(512, 2) void conv_mfma(
    const unsigned short* __restrict__ xin, const uint4* __restrict__ wTq,
    const float* __restrict__ bias, unsigned short* __restrict__ hout,
    float* __restrict__ fout)
{
    constexpr int ICB = IC / 32, WOC = OC / 32;
    constexpr int JT = 2 * WOC;        // 4 conv1
    constexpr int NW = ICB * 5;
    constexpr int NIN = 2880;          // 20 rows * 36 x * 4 chunks
    constexpr int BUF = 20 * 36 * 80;  // 57600 B per buffer
    __shared__ __align__(16) char lds_in[2 * BUF];  // 115.2 KB

    const int tid = threadIdx.x;
    const int wave = tid >> 6, lane = tid & 63;
    const int ln = lane & 31, half = lane >> 5;
    const int ochalf = (WOC == 2) ? (wave >> 2) : 0;
    const int wy = (WOC == 2) ? (wave & 3) : wave;
    const int z = blockIdx.x, ybl = blockIdx.y, b = blockIdx.z;
    const int y0 = ybl * 16;

    const uint4* wTl = wTq + half * 32 + ln;  // lane-fixed chunk offset

    // ---- window-invariant staging geometry (hoisted) ----
    int  goff[6];   // global offset sans (gz, icb) term
    int  loff[6];   // LDS byte offset within a buffer
    bool act[6], yxok[6];
#pragma unroll
    for (int k = 0; k < 6; ++k) {
        int i = tid + 512 * k;
        act[k] = i < NIN;
        int sub = i & 3, cc = i >> 2;
        int x36 = cc % 36, row = cc / 36;
        int gy = y0 - 2 + row, gx = x36 - 2;
        yxok[k] = ((unsigned)gy < 32u) & ((unsigned)gx < 32u);
        goff[k] = (b * 32768 + gy * 32 + gx) * IC + sub * 8;
        loff[k] = row * 2880 + x36 * 80 + sub * 16;
    }

    f32x16 acc[JT];
#pragma unroll
    for (int j = 0; j < JT; ++j)
#pragma unroll
        for (int e = 0; e < 16; ++e) acc[j][e] = 0.f;

    uint4 prei[6];

    auto issue = [&](int icb, int dz) {
        int gz = z + dz - 2;
        bool zok = (unsigned)gz < 32u;
        int zoff = gz * (1024 * IC) + icb * 32;
#pragma unroll
        for (int k = 0; k < 6; ++k) {
            if (act[k]) {
                uint4 v = {0u, 0u, 0u, 0u};
                if (zok & yxok[k])
                    v = *(const uint4*)(xin + goff[k] + zoff);
                prei[k] = v;
            }
        }
    };

    auto stage = [&](int buf) {
        char* base = lds_in + buf * BUF;
#pragma unroll
        for (int k = 0; k < 6; ++k)
            if (act[k]) *(uint4*)(base + loff[k]) = prei[k];
    };

    bf16x8 bufA[5], bufB[5];

    auto fillA = [&](bool valid, int icb, int dz, int dx, int kb,
                     bf16x8 (&buf)[5]) {
        if (!valid) return;
#pragma unroll
        for (int dy = 0; dy < 5; ++dy) {
            int tap = (dz * 5 + dy) * 5 + dx;
            int f = ((tap * ICB + icb) * WOC + ochalf) * 2 + kb;
            buf[dy] = *(const bf16x8*)(wTl + (size_t)f * 64);
        }
    };

    auto compute = [&](const char* base, bf16x8 (&cur)[5], int dx, int kb) {
        bf16x8 brow[JT + 4];
#pragma unroll
        for (int r = 0; r < JT + 4; ++r)
            brow[r] = *(const bf16x8*)(base + (JT * wy + r) * 2880 +
                                       (ln + dx) * 80 + kb * 32 + half * 16);
#pragma unroll
        for (int dy = 0; dy < 5; ++dy)
#pragma unroll
            for (int j = 0; j < JT; ++j)
                acc[j] = __builtin_amdgcn_mfma_f32_32x32x16_bf16(
                    cur[dy], brow[dy + j], acc[j], 0, 0, 0);
    };

    // prologue: fill buf0, prefetch first A fragments
    issue(0, 0);
    fillA(true, 0, 0, 0, 0, bufA);
    stage(0);
    __syncthreads();

    int cur = 0;
    for (int w = 0; w < NW; ++w) {
        int icb = w / 5, dz = w - icb * 5;
        int nw = w + 1;
        int nicb = nw / 5, ndz = nw - nicb * 5;
        bool more = nw < NW;
        const char* rb = lds_in + cur * BUF;

#pragma unroll
        for (int gp = 0; gp < 5; ++gp) {
            fillA(true, icb, dz, gp, 1, bufB);
            compute(rb, bufA, gp, 0);
            if (gp < 4) fillA(true, icb, dz, gp + 1, 0, bufA);
            else        fillA(more, nicb, ndz, 0, 0, bufA);
            if (gp == 0 && more) issue(nicb, ndz);          // next-window loads
            if (gp == 2 && more) stage(cur ^ 1);            // overlapped write
            compute(rb, bufB, gp, 1);
        }
        // one barrier/window: drain only LDS ops; global loads stay in flight
        asm volatile("s_waitcnt lgkmcnt(0)\n\ts_barrier" ::: "memory");
        cur ^= 1;
    }

    __syncthreads();
    if (WRITE_H) {
        // bias + exact GELU, transpose to [x][oc] via LDS scratch (4 y-waves
        // x 32 x x 64 oc rows), store h[b][z][y][x][64] bf16.
#pragma unroll
        for (int j = 0; j < JT; ++j) {
            char* scr = lds_in + wy * (32 * 144);
#pragma unroll
            for (int r = 0; r < 16; ++r) {
                int ocr = (r & 3) + 8 * (r >> 2) + 4 * half;
                int oc = ochalf * 32 + ocr;
                float v = acc[j][r] + bias[oc];
                v = 0.5f * v * (1.f + erff(v * 0.70710678118654752f));
                *(unsigned short*)(scr + ln * 144 + oc * 2) = f2bf(v);
            }
            __syncthreads();
#pragma unroll
            for (int k = 0; k < 2; ++k) {
                int u = tid + 512 * k;          // 1024 = 4 wy * 32 x * 8 un
                int wyi = u >> 8, rem = u & 255;
                int xx = rem >> 3, un = rem & 7;
                uint4 v = *(const uint4*)(lds_in + wyi * (32 * 144) +
                                          xx * 144 + un * 16);
                int y = y0 + 4 * wyi + j;
                *(uint4*)(hout + ((((size_t)b * 32 + z) * 32 + y) * 32 + xx)
                          * 64 + un * 8) = v;
            }
            __syncthreads();
        }
    } else {
        // final: bias + attention (already alpha-scaled in fout) added
#pragma unroll
        for (int j = 0; j < JT; ++j) {
            int y = y0 + JT * wy + j;
#pragma unroll
            for (int r = 0; r < 16; ++r) {
                int oc = (r & 3) + 8 * (r >> 2) + 4 * half;
                size_t o = ((size_t)b * 32 + oc) * S3 + z * 1024 + y * 32 + ln;
                fout[o] = acc[j][r] + bias[oc] + fout[o];
            }
        }
    }
}

// ============ conv2: round-4/7 kb-split kernel — UNCHANGED =================
template <int IC, int OC, bool WRITE_H>
__global__ __launch_bounds__(512, 2) void conv_mfma_ks(
    const unsigned short* __restrict__ xin, const uint4* __restrict__ wTq,
    const float* __restrict__ bias, unsigned short* __restrict__ hout,
    float* __restrict__ fout)
{
    constexpr int ICB = IC / 32, WOC = OC / 32;
    constexpr int JT = (WOC == 2) ? 8 : 4;   // rows per wave (kb-split)
    constexpr int NW = ICB * 5;              // even
    constexpr int NIN = 2880;                // 20 rows * 36 x * 4 chunks
    constexpr int BUF = 20 * 36 * 80;        // 57600 B per buffer
    constexpr int PREI = 6;
    __shared__ __align__(16) char lds_in[2 * BUF];  // 115.2 KB

    const int tid = threadIdx.x;
    const int wave = tid >> 6, lane = tid & 63;
    const int ln = lane & 31, half = lane >> 5;
    const int kbw = wave & 1;                // K-half owned by this wave
    const int w2 = wave >> 1;                // pair id 0..3
    const int ochalf = (WOC == 2) ? (w2 >> 1) : 0;
    const int wy = (WOC == 2) ? (w2 & 1) : w2;
    const int z = blockIdx.x, ybl = blockIdx.y, b = blockIdx.z;
    const int y0 = ybl * 16;

    const uint4* wTl = wTq + half * 32 + ln;  // lane-fixed chunk offset

    // ---- window-invariant staging geometry (hoisted) ----
    int  goff[PREI];   // global offset sans (gz, icb) term
    bool act[PREI], yxok[PREI];
#pragma unroll
    for (int k = 0; k < PREI; ++k) {
        int i = tid + 512 * k;
        act[k] = i < NIN;
        int sub = i & 3, cc = i >> 2;
        int x36 = cc % 36, row = cc / 36;
        int gy = y0 - 2 + row, gx = x36 - 2;
        yxok[k] = ((unsigned)gy < 32u) & ((unsigned)gx < 32u);
        goff[k] = (b * 32768 + gy * 32 + gx) * IC + sub * 8;
    }

    f32x16 acc[JT];
#pragma unroll
    for (int j = 0; j < JT; ++j)
#pragma unroll
        for (int e = 0; e < 16; ++e) acc[j][e] = 0.f;

    uint4 prei[PREI];

    auto issue = [&](int icb, int dz) {
        int gz = z + dz - 2;
        bool zok = (unsigned)gz < 32u;
        int zoff = gz * (1024 * IC) + icb * 32;
#pragma unroll
        for (int k = 0; k < PREI; ++k) {
            if (act[k]) {
                uint4 v = {0u, 0u, 0u, 0u};
                if (zok & yxok[k])
                    v = *(const uint4*)(xin + goff[k] + zoff);
                prei[k] = v;
            }
        }
    };

    auto stage = [&](int buf) {
        char* base = lds_in + buf * BUF;
#pragma unroll
        for (int k = 0; k < PREI; ++k) {
            if (act[k]) {
                int i = tid + 512 * k;          // loff recomputed (VGPR diet)
                int sub = i & 3, cc = i >> 2;
                int row = cc / 36, x36 = cc - row * 36;
                *(uint4*)(base + row * 2880 + x36 * 80 + sub * 16) = prei[k];
            }
        }
    };

    bf16x8 bufA[5], bufB[5];

    // loads only this wave's kb half: 5 fragments (dy) per call
    auto fillA = [&](bool valid, int icb, int dz, int dx, bf16x8 (&buf)[5]) {
        if (!valid) return;
#pragma unroll
        for (int dy = 0; dy < 5; ++dy) {
            int tap = (dz * 5 + dy) * 5 + dx;
            int f = ((tap * ICB + icb) * WOC + ochalf) * 2 + kbw;
            buf[dy] = *(const bf16x8*)(wTl + (size_t)f * 64);
        }
    };

    // JT+4 ds_read_b128 feed 5*JT MFMAs (own kb only)
    auto compute = [&](const char* base, bf16x8 (&cur)[5], int dx) {
        bf16x8 brow[JT + 4];
#pragma unroll
        for (int r = 0; r < JT + 4; ++r)
            brow[r] = *(const bf16x8*)(base + (JT * wy + r) * 2880 +
                                       (ln + dx) * 80 + kbw * 32 + half * 16);
#pragma unroll
        for (int dy = 0; dy < 5; ++dy)
#pragma unroll
            for (int j = 0; j < JT; ++j)
                acc[j] = __builtin_amdgcn_mfma_f32_32x32x16_bf16(
                    cur[dy], brow[dy + j], acc[j], 0, 0, 0);
    };

    int cur = 0;
    auto window = [&](int w, bf16x8 (&X)[5], bf16x8 (&Y)[5]) {
        int icb = w / 5, dz = w - icb * 5;
        int nw = w + 1;
        int nicb = nw / 5, ndz = nw - nicb * 5;
        bool more = nw < NW;
        const char* rb = lds_in + cur * BUF;

        fillA(true, icb, dz, 1, Y);
        if (more) issue(nicb, ndz);         // next-window global loads
        compute(rb, X, 0);
        fillA(true, icb, dz, 2, X);
        compute(rb, Y, 1);
        fillA(true, icb, dz, 3, Y);
        if (more) stage(cur ^ 1);           // overlapped LDS write
        compute(rb, X, 2);
        fillA(true, icb, dz, 4, X);
        compute(rb, Y, 3);
        fillA(more, nicb, ndz, 0, Y);
        compute(rb, X, 4);
        // one barrier/window: drain only LDS ops; global loads stay in flight
        asm volatile("s_waitcnt lgkmcnt(0)\n\ts_barrier" ::: "memory");
        cur ^= 1;
    };

    // prologue: fill buf0, prefetch first A fragments
    issue(0, 0);
    fillA(true, 0, 0, 0, bufA);
    stage(0);
    __syncthreads();

    for (int wp = 0; wp < NW; wp += 2) {
        window(wp, bufA, bufB);
        window(wp + 1, bufB, bufA);
    }

    __syncthreads();
    // ---- cross-wave kb reduction: partner waves (wave^1) sum acc ----
    {
        char* red = lds_in;
#pragma unroll
        for (int rnd = 0; rnd < JT / 4; ++rnd) {
            if (kbw == 1) {
#pragma unroll
                for (int qi = 0; qi < 4; ++qi) {
                    const uint4* src = (const uint4*)&acc[rnd * 4 + qi];
#pragma unroll
                    for (int wd = 0; wd < 4; ++wd)
                        *(uint4*)(red + (w2 * 4 + qi) * 5120 + lane * 80 +
                                  wd * 16) = src[wd];
                }
            }
            __syncthreads();
            if (kbw == 0) {
#pragma unroll
                for (int qi = 0; qi < 4; ++qi) {
#pragma unroll
                    for (int wd = 0; wd < 4; ++wd) {
                        uint4 v = *(const uint4*)(red + (w2 * 4 + qi) * 5120 +
                                                  lane * 80 + wd * 16);
                        acc[rnd * 4 + qi][wd * 4 + 0] += __uint_as_float(v.x);
                        acc[rnd * 4 + qi][wd * 4 + 1] += __uint_as_float(v.y);
                        acc[rnd * 4 + qi][wd * 4 + 2] += __uint_as_float(v.z);
                        acc[rnd * 4 + qi][wd * 4 + 3] += __uint_as_float(v.w);
                    }
                }
            }
            __syncthreads();
        }
    }

    if (WRITE_H) {
#pragma unroll
        for (int j = 0; j < JT; ++j) {
            if (kbw == 0) {
                char* scr = lds_in + wy * (32 * 144);
#pragma unroll
                for (int r = 0; r < 16; ++r) {
                    int ocr = (r & 3) + 8 * (r >> 2) + 4 * half;
                    int oc = ochalf * 32 + ocr;
                    float v = acc[j][r] + bias[oc];
                    v = 0.5f * v * (1.f + erff(v * 0.70710678118654752f));
                    *(unsigned short*)(scr + ln * 144 + oc * 2) = f2bf(v);
                }
            }
            __syncthreads();
            {
                int u = tid;
                int wyi = u >> 8, rem = u & 255;
                int xx = rem >> 3, un = rem & 7;
                uint4 v = *(const uint4*)(lds_in + wyi * (32 * 144) +
                                          xx * 144 + un * 16);
                int y = y0 + 8 * wyi + j;
                *(uint4*)(hout + ((((size_t)b * 32 + z) * 32 + y) * 32 + xx)
                          * 64 + un * 8) = v;
            }
            __syncthreads();
        }
    } else {
        // final: bias + attention (already alpha-scaled in fout) added
        if (kbw == 0) {
#pragma unroll
            for (int j = 0; j < JT; ++j) {
                int y = y0 + JT * wy + j;
#pragma unroll
                for (int r = 0; r < 16; ++r) {
                    int oc = (r & 3) + 8 * (r >> 2) + 4 * half;
                    size_t o = ((size_t)b * 32 + oc) * S3 + z * 1024 + y * 32 + ln;
                    fout[o] = acc[j][r] + bias[oc] + fout[o];
                }
            }
        }
    }
}

// ---------------------------------------------------------------------------
extern "C" void kernel_launch(void* const* d_in, const int* in_sizes, int n_in,
                              void* d_out, int out_size, void* d_ws, size_t ws_size,
                              hipStream_t stream)
{
    const float* x       = (const float*)d_in[0];
    const float* basis   = (const float*)d_in[1];
    const float* mixer   = (const float*)d_in[2];
    const float* wq      = (const float*)d_in[3];
    const float* wk      = (const float*)d_in[4];
    const float* wv      = (const float*)d_in[5];
    const float* conv1_w = (const float*)d_in[6];
    const float* conv1_b = (const float*)d_in[7];
    const float* conv2_w = (const float*)d_in[8];
    const float* conv2_b = (const float*)d_in[9];
    const float* alpha   = (const float*)d_in[10];
    float* out = (float*)d_out;

    char* wsb = (char*)d_ws;
    unsigned short* xb   = (unsigned short*)wsb;               // 32 MiB
    unsigned short* h    = (unsigned short*)(wsb + 33554432);  // 16 MiB
    // tokb/qbuf alias h: both dead before conv1 writes h (same stream order)
    unsigned short* tokb = (unsigned short*)(wsb + 33554432);  // 2 MiB
    float* qbuf          = (float*)(wsb + 37748736);           // 4 MiB
    unsigned short* wT1  = (unsigned short*)(wsb + 50331648);  // 2 MiB
    unsigned short* wT2  = (unsigned short*)(wsb + 52379648);  // 0.5 MiB

    wt_transpose<128, 64><<<64, 256, 0, stream>>>(conv1_w, wT1);
    wt_transpose<64, 32><<<32, 256, 0, stream>>>(conv2_w, wT2);
    xb_transpose<<<dim3(1024, 4), 256, 0, stream>>>(x, xb);

    token_q_kernel<<<S3 / 256, 256, 0, stream>>>(basis, mixer, wq, tokb, qbuf);
    attention_mfma<<<1024, 256, 0, stream>>>(xb, tokb, qbuf, wk, wv, alpha,
                                             out);

    conv_mfma<128, 64, true><<<dim3(32, 2, 4), 512, 0, stream>>>(
        xb, (const uint4*)wT1, conv1_b, h, nullptr);
    conv_mfma_ks<64, 32, false><<<dim3(32, 2, 4), 512, 0, stream>>>(
        h, (const uint4*)wT2, conv2_b, nullptr, out);
}

// Round 12
// 429.711 us; speedup vs baseline: 1.0824x; 1.0824x over previous
//
#include <hip/hip_runtime.h>
#include <cstddef>
#include <cstdint>

#define S3 32768  // 32*32*32 spatial positions

typedef short bf16x8 __attribute__((ext_vector_type(8)));   // 8 bf16 in 4 VGPRs
typedef float f32x16 __attribute__((ext_vector_type(16)));

static __device__ inline unsigned short f2bf(float f) {
    unsigned int u = __float_as_uint(f);
    unsigned int r = (u + 0x7FFFu + ((u >> 16) & 1u)) >> 16;  // RNE
    return (unsigned short)r;
}

static __device__ inline float bf2f(unsigned short u) {
    return __uint_as_float(((unsigned)u) << 16);
}

// --------- weight transpose: wT[tap][icb][c][kb][chunk(=half*32+ln)][8ic] --
// r11 LDS-tiled coalesced version (measured neutral vs old — source tensors
// are L2-resident — kept for cleanliness).
template <int IC, int OC>
__global__ __launch_bounds__(256) void wt_transpose(
    const float* __restrict__ w, unsigned short* __restrict__ wT)
{
    constexpr int ICB = IC / 32, WOC = OC / 32;
    constexpr int NFLAT = IC * 125;          // floats per oc (divisible by 4)
    constexpr int NRUNS = 125 * ICB * 4;     // uint4 runs per oc
    __shared__ unsigned short tile[IC][130];
    const int oc = blockIdx.x, tid = threadIdx.x;
    const int ln = oc & 31, c = oc >> 5;
    const float* src = w + (size_t)oc * NFLAT;

    for (int f = tid; f < NFLAT / 4; f += 256) {
        float4 v = *(const float4*)(src + f * 4);
        float vv[4] = {v.x, v.y, v.z, v.w};
#pragma unroll
        for (int i = 0; i < 4; ++i) {
            int flat = f * 4 + i;
            int ic = flat / 125, tap = flat - ic * 125;
            tile[ic][tap] = f2bf(vv[i]);
        }
    }
    __syncthreads();
    for (int r = tid; r < NRUNS; r += 256) {
        int tap = r / (ICB * 4);
        int rem = r - tap * (ICB * 4);
        int icb = rem >> 2, kb = (rem >> 1) & 1, half = rem & 1;
        int ic0 = icb * 32 + kb * 16 + half * 8;
        __align__(16) unsigned short tmp[8];
#pragma unroll
        for (int e = 0; e < 8; ++e) tmp[e] = tile[ic0 + e][tap];
        size_t t = ((((size_t)(tap * ICB + icb) * WOC + c) * 2 + kb) * 64 +
                    half * 32 + ln) * 8;
        *(uint4*)(wT + t) = *(const uint4*)tmp;
    }
}

// ---------------- x transpose: xb[b][z][y][x][128 ic] bf16 -----------------
__global__ __launch_bounds__(256) void xb_transpose(
    const float* __restrict__ x, unsigned short* __restrict__ xb)
{
    __shared__ float tile[32][133];
    int zy = blockIdx.x, b = blockIdx.y;
    int t = threadIdx.x, xi = t & 31, ich = t >> 5;
#pragma unroll
    for (int k = 0; k < 16; ++k) {
        int ic = k * 8 + ich;
        tile[xi][ic] = x[(size_t)(b * 128 + ic) * S3 + zy * 32 + xi];
    }
    __syncthreads();
#pragma unroll
    for (int k = 0; k < 2; ++k) {
        int u = t + 256 * k;
        int xx = u >> 4, j = u & 15;
        __align__(16) unsigned short tmp[8];
#pragma unroll
        for (int e = 0; e < 8; ++e) tmp[e] = f2bf(tile[xx][j * 8 + e]);
        *(uint4*)(xb + ((size_t)b * S3 + zy * 32 + xx) * 128 + j * 8) =
            *(const uint4*)tmp;
    }
}

// ---- attention via MFMA, NOW WITH token+q FUSED IN (r12) ------------------
// r10's MFMA attention (measured win) + token_q folded in:
//  * tok B-fragment computed IN-LANE: lane (ln,half) needs exactly channels
//    kb*16+half*8+e of its own position s0+ln -> 128 fma from 8 coalesced
//    basis loads + wave-uniform mixer (scalar path). Replaces the tokb
//    buffer (2MB write + 2MB read) and the j=4 global loads.
//  * q = wq[4] @ tok done as 2 MFMAs (A=Wq4 fragment, B=tok fragment); the
//    C-tile IS the qv[16] layout consumed by the QK^T reduction. Replaces
//    qbuf (4MB write + 4MB read) and the whole token_q kernel launch.
// Fragment conventions (PROVEN in conv + r10 attention):
//   A: lane(ln,half) holds W[oc=ln][c=kb*16+half*8+e]
//   B: lane(ln,half) holds X[c=kb*16+half*8+e][col=ln]
//   C: reg r -> row=(r&3)+8*(r>>2)+4*half, col=ln
__global__ __launch_bounds__(256) void attention_mfma(
    const unsigned short* __restrict__ xb, const float* __restrict__ basis,
    const float* __restrict__ mixer, const float* __restrict__ wq,
    const float* __restrict__ wk, const float* __restrict__ wv,
    const float* __restrict__ alpha_p, float* __restrict__ out)
{
    const int wave = threadIdx.x >> 6, lane = threadIdx.x & 63;
    const int ln = lane & 31, half = lane >> 5;
    const int tl = blockIdx.x * 4 + wave;     // 4096 tiles
    const int g0 = tl * 32;
    const int b = g0 >> 15;
    const int s0 = g0 & (S3 - 1);

    // ---- A fragments: Wq4/Wk/Wv, loaded once per wave (L2-hot) ----
    bf16x8 aq[2], ak[5][2], av[5][2];
#pragma unroll
    for (int kb = 0; kb < 2; ++kb) {
        const float* qs = wq + 4 * 1024 + ln * 32 + kb * 16 + half * 8;
        bf16x8 tq;
#pragma unroll
        for (int e = 0; e < 8; ++e) tq[e] = (short)f2bf(qs[e]);
        aq[kb] = tq;
    }
#pragma unroll
    for (int j = 0; j < 5; ++j)
#pragma unroll
        for (int kb = 0; kb < 2; ++kb) {
            const float* ks = wk + ((j * 32 + ln) * 32 + kb * 16 + half * 8);
            const float* vs = wv + ((j * 32 + ln) * 32 + kb * 16 + half * 8);
            bf16x8 tk, tv;
#pragma unroll
            for (int e = 0; e < 8; ++e) {
                tk[e] = (short)f2bf(ks[e]);
                tv[e] = (short)f2bf(vs[e]);
            }
            ak[j][kb] = tk;
            av[j][kb] = tv;
        }

    // ---- tok fragment in-lane: channels kb*16+half*8+e of position s0+ln --
    float bv[8];
#pragma unroll
    for (int r = 0; r < 8; ++r) bv[r] = basis[r * S3 + s0 + ln];
    bf16x8 tokf[2];
#pragma unroll
    for (int kb = 0; kb < 2; ++kb) {
        bf16x8 tf;
#pragma unroll
        for (int e = 0; e < 8; ++e) {
            int c = kb * 16 + half * 8 + e;
            float t = 0.f;
#pragma unroll
            for (int r = 0; r < 8; ++r) t += mixer[c * 8 + r] * bv[r];
            tf[e] = (short)f2bf(t);
        }
        tokf[kb] = tf;
    }

    // ---- q = Wq4 @ tok via MFMA: C-tile IS qv[16] (row(r,half), col ln) ---
    f32x16 qc;
#pragma unroll
    for (int e = 0; e < 16; ++e) qc[e] = 0.f;
    qc = __builtin_amdgcn_mfma_f32_32x32x16_bf16(aq[0], tokf[0], qc, 0, 0, 0);
    qc = __builtin_amdgcn_mfma_f32_32x32x16_bf16(aq[1], tokf[1], qc, 0, 0, 0);

    const unsigned short* xrow = xb + ((size_t)b * S3 + s0 + ln) * 128;

    auto loadB = [&](int j, int kb) -> bf16x8 {
        if (j < 4)
            return *(const bf16x8*)(xrow + j * 32 + kb * 16 + half * 8);
        else
            return tokf[kb];
    };

    // ---- QK^T pass ----
    const float scale = 0.17677669529663687f;
    float l[5];
#pragma unroll
    for (int j = 0; j < 5; ++j) {
        bf16x8 b0 = loadB(j, 0), b1 = loadB(j, 1);
        f32x16 c;
#pragma unroll
        for (int e = 0; e < 16; ++e) c[e] = 0.f;
        c = __builtin_amdgcn_mfma_f32_32x32x16_bf16(ak[j][0], b0, c, 0, 0, 0);
        c = __builtin_amdgcn_mfma_f32_32x32x16_bf16(ak[j][1], b1, c, 0, 0, 0);
        float part = 0.f;
#pragma unroll
        for (int r = 0; r < 16; ++r) part += c[r] * qc[r];
        part += __shfl_xor(part, 32);     // combine the two half rows
        l[j] = part * scale;
    }

    // ---- softmax (lane-local: each lane owns its column) ----
    float m = l[0];
#pragma unroll
    for (int j = 1; j < 5; ++j) m = fmaxf(m, l[j]);
    float p[5], sum = 0.f;
#pragma unroll
    for (int j = 0; j < 5; ++j) { p[j] = __expf(l[j] - m); sum += p[j]; }
    float inv = alpha_p[0] / sum;

    // ---- PV pass: p_j folded into B operand (per-lane = per-column) ----
    f32x16 ov;
#pragma unroll
    for (int e = 0; e < 16; ++e) ov[e] = 0.f;
#pragma unroll
    for (int j = 0; j < 5; ++j) {
        float pj = p[j];
#pragma unroll
        for (int kb = 0; kb < 2; ++kb) {
            bf16x8 bx = loadB(j, kb);
            bf16x8 pb;
#pragma unroll
            for (int e = 0; e < 8; ++e)
                pb[e] = (short)f2bf(bf2f((unsigned short)bx[e]) * pj);
            ov = __builtin_amdgcn_mfma_f32_32x32x16_bf16(av[j][kb], pb, ov,
                                                         0, 0, 0);
        }
    }

    // ---- write: out[(b*32+row)][s0+ln] (half-wave rows cover all 32 oc) ----
#pragma unroll
    for (int r = 0; r < 16; ++r) {
        int row = (r & 3) + 8 * (r >> 2) + 4 * half;
        out[((size_t)b * 32 + row) * S3 + s0 + ln] = ov[r] * inv;
    }
}

// ============ conv1: round-1 exact kernel (219.5 µs r10 — FROZEN) ==========
// 512-thread block (8 waves), 1 block/CU, block tile OC x (16y x 32x) x 1z.
// 2 oc-halves x 4 y-waves, JT=4. LDS input double-buffer, stage overlapped
// at gp==2, one raw lgkmcnt(0)+s_barrier per window. kb-split conv1
// ABANDONED (r4: spill; r8: diet still spilled + broke latency hiding).
template <int IC, int OC, bool WRITE_H>
__global__ __launch_bounds__(512, 2) void conv_mfma(
    const unsigned short* __restrict__ xin, const uint4* __restrict__ wTq,
    const float* __restrict__ bias, unsigned short* __restrict__ hout,
    float* __restrict__ fout)
{
    constexpr int ICB = IC / 32, WOC = OC / 32;
    constexpr int JT = 2 * WOC;        // 4 conv1
    constexpr int NW = ICB * 5;
    constexpr int NIN = 2880;          // 20 rows * 36 x * 4 chunks
    constexpr int BUF = 20 * 36 * 80;  // 57600 B per buffer
    __shared__ __align__(16) char lds_in[2 * BUF];  // 115.2 KB

    const int tid = threadIdx.x;
    const int wave = tid >> 6, lane = tid & 63;
    const int ln = lane & 31, half = lane >> 5;
    const int ochalf = (WOC == 2) ? (wave >> 2) : 0;
    const int wy = (WOC == 2) ? (wave & 3) : wave;
    const int z = blockIdx.x, ybl = blockIdx.y, b = blockIdx.z;
    const int y0 = ybl * 16;

    const uint4* wTl = wTq + half * 32 + ln;  // lane-fixed chunk offset

    // ---- window-invariant staging geometry (hoisted) ----
    int  goff[6];   // global offset sans (gz, icb) term
    int  loff[6];   // LDS byte offset within a buffer
    bool act[6], yxok[6];
#pragma unroll
    for (int k = 0; k < 6; ++k) {
        int i = tid + 512 * k;
        act[k] = i < NIN;
        int sub = i & 3, cc = i >> 2;
        int x36 = cc % 36, row = cc / 36;
        int gy = y0 - 2 + row, gx = x36 - 2;
        yxok[k] = ((unsigned)gy < 32u) & ((unsigned)gx < 32u);
        goff[k] = (b * 32768 + gy * 32 + gx) * IC + sub * 8;
        loff[k] = row * 2880 + x36 * 80 + sub * 16;
    }

    f32x16 acc[JT];
#pragma unroll
    for (int j = 0; j < JT; ++j)
#pragma unroll
        for (int e = 0; e < 16; ++e) acc[j][e] = 0.f;

    uint4 prei[6];

    auto issue = [&](int icb, int dz) {
        int gz = z + dz - 2;
        bool zok = (unsigned)gz < 32u;
        int zoff = gz * (1024 * IC) + icb * 32;
#pragma unroll
        for (int k = 0; k < 6; ++k) {
            if (act[k]) {
                uint4 v = {0u, 0u, 0u, 0u};
                if (zok & yxok[k])
                    v = *(const uint4*)(xin + goff[k] + zoff);
                prei[k] = v;
            }
        }
    };

    auto stage = [&](int buf) {
        char* base = lds_in + buf * BUF;
#pragma unroll
        for (int k = 0; k < 6; ++k)
            if (act[k]) *(uint4*)(base + loff[k]) = prei[k];
    };

    bf16x8 bufA[5], bufB[5];

    auto fillA = [&](bool valid, int icb, int dz, int dx, int kb,
                     bf16x8 (&buf)[5]) {
        if (!valid) return;
#pragma unroll
        for (int dy = 0; dy < 5; ++dy) {
            int tap = (dz * 5 + dy) * 5 + dx;
            int f = ((tap * ICB + icb) * WOC + ochalf) * 2 + kb;
            buf[dy] = *(const bf16x8*)(wTl + (size_t)f * 64);
        }
    };

    auto compute = [&](const char* base, bf16x8 (&cur)[5], int dx, int kb) {
        bf16x8 brow[JT + 4];
#pragma unroll
        for (int r = 0; r < JT + 4; ++r)
            brow[r] = *(const bf16x8*)(base + (JT * wy + r) * 2880 +
                                       (ln + dx) * 80 + kb * 32 + half * 16);
#pragma unroll
        for (int dy = 0; dy < 5; ++dy)
#pragma unroll
            for (int j = 0; j < JT; ++j)
                acc[j] = __builtin_amdgcn_mfma_f32_32x32x16_bf16(
                    cur[dy], brow[dy + j], acc[j], 0, 0, 0);
    };

    // prologue: fill buf0, prefetch first A fragments
    issue(0, 0);
    fillA(true, 0, 0, 0, 0, bufA);
    stage(0);
    __syncthreads();

    int cur = 0;
    for (int w = 0; w < NW; ++w) {
        int icb = w / 5, dz = w - icb * 5;
        int nw = w + 1;
        int nicb = nw / 5, ndz = nw - nicb * 5;
        bool more = nw < NW;
        const char* rb = lds_in + cur * BUF;

#pragma unroll
        for (int gp = 0; gp < 5; ++gp) {
            fillA(true, icb, dz, gp, 1, bufB);
            compute(rb, bufA, gp, 0);
            if (gp < 4) fillA(true, icb, dz, gp + 1, 0, bufA);
            else        fillA(more, nicb, ndz, 0, 0, bufA);
            if (gp == 0 && more) issue(nicb, ndz);          // next-window loads
            if (gp == 2 && more) stage(cur ^ 1);            // overlapped write
            compute(rb, bufB, gp, 1);
        }
        // one barrier/window: drain only LDS ops; global loads stay in flight
        asm volatile("s_waitcnt lgkmcnt(0)\n\ts_barrier" ::: "memory");
        cur ^= 1;
    }

    __syncthreads();
    if (WRITE_H) {
        // bias + exact GELU, transpose to [x][oc] via LDS scratch (4 y-waves
        // x 32 x x 64 oc rows), store h[b][z][y][x][64] bf16.
#pragma unroll
        for (int j = 0; j < JT; ++j) {
            char* scr = lds_in + wy * (32 * 144);
#pragma unroll
            for (int r = 0; r < 16; ++r) {
                int ocr = (r & 3) + 8 * (r >> 2) + 4 * half;
                int oc = ochalf * 32 + ocr;
                float v = acc[j][r] + bias[oc];
                v = 0.5f * v * (1.f + erff(v * 0.70710678118654752f));
                *(unsigned short*)(scr + ln * 144 + oc * 2) = f2bf(v);
            }
            __syncthreads();
#pragma unroll
            for (int k = 0; k < 2; ++k) {
                int u = tid + 512 * k;          // 1024 = 4 wy * 32 x * 8 un
                int wyi = u >> 8, rem = u & 255;
                int xx = rem >> 3, un = rem & 7;
                uint4 v = *(const uint4*)(lds_in + wyi * (32 * 144) +
                                          xx * 144 + un * 16);
                int y = y0 + 4 * wyi + j;
                *(uint4*)(hout + ((((size_t)b * 32 + z) * 32 + y) * 32 + xx)
                          * 64 + un * 8) = v;
            }
            __syncthreads();
        }
    } else {
        // final: bias + attention (already alpha-scaled in fout) added
#pragma unroll
        for (int j = 0; j < JT; ++j) {
            int y = y0 + JT * wy + j;
#pragma unroll
            for (int r = 0; r < 16; ++r) {
                int oc = (r & 3) + 8 * (r >> 2) + 4 * half;
                size_t o = ((size_t)b * 32 + oc) * S3 + z * 1024 + y * 32 + ln;
                fout[o] = acc[j][r] + bias[oc] + fout[o];
            }
        }
    }
}

// ============ conv2: round-4/7 kb-split kernel — FROZEN ====================
template <int IC, int OC, bool WRITE_H>
__global__ __launch_bounds__(512, 2) void conv_mfma_ks(
    const unsigned short* __restrict__ xin, const uint4* __restrict__ wTq,
    const float* __restrict__ bias, unsigned short* __restrict__ hout,
    float* __restrict__ fout)
{
    constexpr int ICB = IC / 32, WOC = OC / 32;
    constexpr int JT = (WOC == 2) ? 8 : 4;   // rows per wave (kb-split)
    constexpr int NW = ICB * 5;              // even
    constexpr int NIN = 2880;                // 20 rows * 36 x * 4 chunks
    constexpr int BUF = 20 * 36 * 80;        // 57600 B per buffer
    constexpr int PREI = 6;
    __shared__ __align__(16) char lds_in[2 * BUF];  // 115.2 KB

    const int tid = threadIdx.x;
    const int wave = tid >> 6, lane = tid & 63;
    const int ln = lane & 31, half = lane >> 5;
    const int kbw = wave & 1;                // K-half owned by this wave
    const int w2 = wave >> 1;                // pair id 0..3
    const int ochalf = (WOC == 2) ? (w2 >> 1) : 0;
    const int wy = (WOC == 2) ? (w2 & 1) : w2;
    const int z = blockIdx.x, ybl = blockIdx.y, b = blockIdx.z;
    const int y0 = ybl * 16;

    const uint4* wTl = wTq + half * 32 + ln;  // lane-fixed chunk offset

    // ---- window-invariant staging geometry (hoisted) ----
    int  goff[PREI];   // global offset sans (gz, icb) term
    bool act[PREI], yxok[PREI];
#pragma unroll
    for (int k = 0; k < PREI; ++k) {
        int i = tid + 512 * k;
        act[k] = i < NIN;
        int sub = i & 3, cc = i >> 2;
        int x36 = cc % 36, row = cc / 36;
        int gy = y0 - 2 + row, gx = x36 - 2;
        yxok[k] = ((unsigned)gy < 32u) & ((unsigned)gx < 32u);
        goff[k] = (b * 32768 + gy * 32 + gx) * IC + sub * 8;
    }

    f32x16 acc[JT];
#pragma unroll
    for (int j = 0; j < JT; ++j)
#pragma unroll
        for (int e = 0; e < 16; ++e) acc[j][e] = 0.f;

    uint4 prei[PREI];

    auto issue = [&](int icb, int dz) {
        int gz = z + dz - 2;
        bool zok = (unsigned)gz < 32u;
        int zoff = gz * (1024 * IC) + icb * 32;
#pragma unroll
        for (int k = 0; k < PREI; ++k) {
            if (act[k]) {
                uint4 v = {0u, 0u, 0u, 0u};
                if (zok & yxok[k])
                    v = *(const uint4*)(xin + goff[k] + zoff);
                prei[k] = v;
            }
        }
    };

    auto stage = [&](int buf) {
        char* base = lds_in + buf * BUF;
#pragma unroll
        for (int k = 0; k < PREI; ++k) {
            if (act[k]) {
                int i = tid + 512 * k;          // loff recomputed (VGPR diet)
                int sub = i & 3, cc = i >> 2;
                int row = cc / 36, x36 = cc - row * 36;
                *(uint4*)(base + row * 2880 + x36 * 80 + sub * 16) = prei[k];
            }
        }
    };

    bf16x8 bufA[5], bufB[5];

    // loads only this wave's kb half: 5 fragments (dy) per call
    auto fillA = [&](bool valid, int icb, int dz, int dx, bf16x8 (&buf)[5]) {
        if (!valid) return;
#pragma unroll
        for (int dy = 0; dy < 5; ++dy) {
            int tap = (dz * 5 + dy) * 5 + dx;
            int f = ((tap * ICB + icb) * WOC + ochalf) * 2 + kbw;
            buf[dy] = *(const bf16x8*)(wTl + (size_t)f * 64);
        }
    };

    // JT+4 ds_read_b128 feed 5*JT MFMAs (own kb only)
    auto compute = [&](const char* base, bf16x8 (&cur)[5], int dx) {
        bf16x8 brow[JT + 4];
#pragma unroll
        for (int r = 0; r < JT + 4; ++r)
            brow[r] = *(const bf16x8*)(base + (JT * wy + r) * 2880 +
                                       (ln + dx) * 80 + kbw * 32 + half * 16);
#pragma unroll
        for (int dy = 0; dy < 5; ++dy)
#pragma unroll
            for (int j = 0; j < JT; ++j)
                acc[j] = __builtin_amdgcn_mfma_f32_32x32x16_bf16(
                    cur[dy], brow[dy + j], acc[j], 0, 0, 0);
    };

    int cur = 0;
    auto window = [&](int w, bf16x8 (&X)[5], bf16x8 (&Y)[5]) {
        int icb = w / 5, dz = w - icb * 5;
        int nw = w + 1;
        int nicb = nw / 5, ndz = nw - nicb * 5;
        bool more = nw < NW;
        const char* rb = lds_in + cur * BUF;

        fillA(true, icb, dz, 1, Y);
        if (more) issue(nicb, ndz);         // next-window global loads
        compute(rb, X, 0);
        fillA(true, icb, dz, 2, X);
        compute(rb, Y, 1);
        fillA(true, icb, dz, 3, Y);
        if (more) stage(cur ^ 1);           // overlapped LDS write
        compute(rb, X, 2);
        fillA(true, icb, dz, 4, X);
        compute(rb, Y, 3);
        fillA(more, nicb, ndz, 0, Y);
        compute(rb, X, 4);
        // one barrier/window: drain only LDS ops; global loads stay in flight
        asm volatile("s_waitcnt lgkmcnt(0)\n\ts_barrier" ::: "memory");
        cur ^= 1;
    };

    // prologue: fill buf0, prefetch first A fragments
    issue(0, 0);
    fillA(true, 0, 0, 0, bufA);
    stage(0);
    __syncthreads();

    for (int wp = 0; wp < NW; wp += 2) {
        window(wp, bufA, bufB);
        window(wp + 1, bufB, bufA);
    }

    __syncthreads();
    // ---- cross-wave kb reduction: partner waves (wave^1) sum acc ----
    {
        char* red = lds_in;
#pragma unroll
        for (int rnd = 0; rnd < JT / 4; ++rnd) {
            if (kbw == 1) {
#pragma unroll
                for (int qi = 0; qi < 4; ++qi) {
                    const uint4* src = (const uint4*)&acc[rnd * 4 + qi];
#pragma unroll
                    for (int wd = 0; wd < 4; ++wd)
                        *(uint4*)(red + (w2 * 4 + qi) * 5120 + lane * 80 +
                                  wd * 16) = src[wd];
                }
            }
            __syncthreads();
            if (kbw == 0) {
#pragma unroll
                for (int qi = 0; qi < 4; ++qi) {
#pragma unroll
                    for (int wd = 0; wd < 4; ++wd) {
                        uint4 v = *(const uint4*)(red + (w2 * 4 + qi) * 5120 +
                                                  lane * 80 + wd * 16);
                        acc[rnd * 4 + qi][wd * 4 + 0] += __uint_as_float(v.x);
                        acc[rnd * 4 + qi][wd * 4 + 1] += __uint_as_float(v.y);
                        acc[rnd * 4 + qi][wd * 4 + 2] += __uint_as_float(v.z);
                        acc[rnd * 4 + qi][wd * 4 + 3] += __uint_as_float(v.w);
                    }
                }
            }
            __syncthreads();
        }
    }

    if (WRITE_H) {
#pragma unroll
        for (int j = 0; j < JT; ++j) {
            if (kbw == 0) {
                char* scr = lds_in + wy * (32 * 144);
#pragma unroll
                for (int r = 0; r < 16; ++r) {
                    int ocr = (r & 3) + 8 * (r >> 2) + 4 * half;
                    int oc = ochalf * 32 + ocr;
                    float v = acc[j][r] + bias[oc];
                    v = 0.5f * v * (1.f + erff(v * 0.70710678118654752f));
                    *(unsigned short*)(scr + ln * 144 + oc * 2) = f2bf(v);
                }
            }
            __syncthreads();
            {
                int u = tid;
                int wyi = u >> 8, rem = u & 255;
                int xx = rem >> 3, un = rem & 7;
                uint4 v = *(const uint4*)(lds_in + wyi * (32 * 144) +
                                          xx * 144 + un * 16);
                int y = y0 + 8 * wyi + j;
                *(uint4*)(hout + ((((size_t)b * 32 + z) * 32 + y) * 32 + xx)
                          * 64 + un * 8) = v;
            }
            __syncthreads();
        }
    } else {
        // final: bias + attention (already alpha-scaled in fout) added
        if (kbw == 0) {
#pragma unroll
            for (int j = 0; j < JT; ++j) {
                int y = y0 + JT * wy + j;
#pragma unroll
                for (int r = 0; r < 16; ++r) {
                    int oc = (r & 3) + 8 * (r >> 2) + 4 * half;
                    size_t o = ((size_t)b * 32 + oc) * S3 + z * 1024 + y * 32 + ln;
                    fout[o] = acc[j][r] + bias[oc] + fout[o];
                }
            }
        }
    }
}

// ---------------------------------------------------------------------------
extern "C" void kernel_launch(void* const* d_in, const int* in_sizes, int n_in,
                              void* d_out, int out_size, void* d_ws, size_t ws_size,
                              hipStream_t stream)
{
    const float* x       = (const float*)d_in[0];
    const float* basis   = (const float*)d_in[1];
    const float* mixer   = (const float*)d_in[2];
    const float* wq      = (const float*)d_in[3];
    const float* wk      = (const float*)d_in[4];
    const float* wv      = (const float*)d_in[5];
    const float* conv1_w = (const float*)d_in[6];
    const float* conv1_b = (const float*)d_in[7];
    const float* conv2_w = (const float*)d_in[8];
    const float* conv2_b = (const float*)d_in[9];
    const float* alpha   = (const float*)d_in[10];
    float* out = (float*)d_out;

    char* wsb = (char*)d_ws;
    unsigned short* xb   = (unsigned short*)wsb;               // 32 MiB
    unsigned short* h    = (unsigned short*)(wsb + 33554432);  // 16 MiB
    unsigned short* wT1  = (unsigned short*)(wsb + 50331648);  // 2 MiB
    unsigned short* wT2  = (unsigned short*)(wsb + 52379648);  // 0.5 MiB

    wt_transpose<128, 64><<<64, 256, 0, stream>>>(conv1_w, wT1);
    wt_transpose<64, 32><<<32, 256, 0, stream>>>(conv2_w, wT2);
    xb_transpose<<<dim3(1024, 4), 256, 0, stream>>>(x, xb);

    attention_mfma<<<1024, 256, 0, stream>>>(xb, basis, mixer, wq, wk, wv,
                                             alpha, out);

    conv_mfma<128, 64, true><<<dim3(32, 2, 4), 512, 0, stream>>>(
        xb, (const uint4*)wT1, conv1_b, h, nullptr);
    conv_mfma_ks<64, 32, false><<<dim3(32, 2, 4), 512, 0, stream>>>(
        h, (const uint4*)wT2, conv2_b, nullptr, out);
}